// Round 9
// baseline (183.137 us; speedup 1.0000x reference)
//
#include <hip/hip_runtime.h>
#include <hip/hip_bf16.h>

typedef __attribute__((ext_vector_type(8))) short short8;
typedef __attribute__((ext_vector_type(4))) float f32x4;
typedef __attribute__((address_space(1))) const void gvoid_t;
typedef __attribute__((address_space(3))) void lvoid_t;

#define NB 4096   // B
#define DD 256    // D
#define TWOB 8192

__device__ __forceinline__ unsigned short f2bf(float f) {
  unsigned int u = __float_as_uint(f);
  u += 0x7fffu + ((u >> 16) & 1u);
  return (unsigned short)(u >> 16);
}
__device__ __forceinline__ float bf2f(unsigned short s) {
  return __uint_as_float(((unsigned int)s) << 16);
}

// ws float layout: [0..8191] den, [8192..9215] vsum, scal = wsf+9216 (16):
//   scal[0]=psum, scal[2..5]=counts
// arrive tree (uint): 64 leaves at wsf+9232 spaced 32 uints (128B lines),
// root at wsf+11280. Zeroed by kernel A blocks 0..47.
//
// R8 post-mortem: per-ROUND time (wall / (blocks/768)) is 28us in the 1D
// half-grid vs 11.2us in R1's 2D full grid with IDENTICAL inner code; the
// only unreproduced R1 properties were the 2D (64,64) dispatch shape and
// LDS exactly 32768 (R4-R8's 33280 may cross an LDS granule -> occupancy
// 36%->22%). This round restores both: 2D grid with tc<tr holes (16 holes
// do gsum), tail scratch aliased onto As/Bs.

// ---------------- kernel A: zero accum region; normalize -> znb bf16 ------
__global__ __launch_bounds__(256) void norm_kernel(const float* __restrict__ zi,
                                                   const float* __restrict__ zj,
                                                   float* __restrict__ wsf,
                                                   unsigned short* __restrict__ znb) {
  if (blockIdx.x < 48) wsf[blockIdx.x * 256 + threadIdx.x] = 0.f;
  const int lane = threadIdx.x & 63, wave = threadIdx.x >> 6;
  const int i = blockIdx.x * 4 + wave;

  float4 a = ((const float4*)(zi + (size_t)i * DD))[lane];
  float4 b = ((const float4*)(zj + (size_t)i * DD))[lane];
  float sa = a.x * a.x + a.y * a.y + a.z * a.z + a.w * a.w;
  float sb = b.x * b.x + b.y * b.y + b.z * b.z + b.w * b.w;
#pragma unroll
  for (int m = 32; m >= 1; m >>= 1) {
    sa += __shfl_xor(sa, m);
    sb += __shfl_xor(sb, m);
  }
  float ra = 1.0f / fmaxf(sqrtf(sa), 1e-8f);
  float rb = 1.0f / fmaxf(sqrtf(sb), 1e-8f);
  ushort4 oa, ob;
  oa.x = f2bf(a.x * ra); oa.y = f2bf(a.y * ra); oa.z = f2bf(a.z * ra); oa.w = f2bf(a.w * ra);
  ob.x = f2bf(b.x * rb); ob.y = f2bf(b.y * rb); ob.z = f2bf(b.z * rb); ob.w = f2bf(b.w * rb);
  ((ushort4*)(znb + (size_t)i * DD))[lane] = oa;
  ((ushort4*)(znb + (size_t)(i + NB) * DD))[lane] = ob;
}

// ---------------- kernel B: (64,64) grid; tc>=tr tiles; holes gsum/exit ---
__global__ __launch_bounds__(256, 3) void main_kernel(const int* __restrict__ sf,
                                                      float* __restrict__ wsf,
                                                      const unsigned short* __restrict__ znb,
                                                      float* __restrict__ out) {
  __shared__ __align__(16) unsigned short As[2][4096];  // 2 x 8KB
  __shared__ __align__(16) unsigned short Bs[2][4096];
  // tail scratch aliased onto tile LDS (dead after tile phase) -> LDS = 32768
  float* sred = (float*)&As[0][0];
  int* sh_lastp = (int*)&Bs[0][0];

  float* den = wsf;
  float* vsum = wsf + 8192;
  float* scal = wsf + 9216;
  unsigned* leaves = (unsigned*)(wsf + 9232);  // 64 counters, stride 32 uints
  unsigned* root = (unsigned*)(wsf + 11280);

  const int tid = threadIdx.x;
  const int lane = tid & 63, wave = tid >> 6;
  const unsigned tc = blockIdx.x, tr = blockIdx.y;

  if (tc < tr) {
    // ---- hole block: 16 of them do the gsum role, then arrive & exit ----
    if (tc == 0u && tr >= 1u && tr <= 16u) {
      const int r0 = (int)(tr - 1u) * 256;
      {
        int g = sf[r0 + tid];
#pragma unroll
        for (int q = 0; q < 4; ++q) {
          unsigned long long m = __ballot(g == q);
          if (lane == 0) unsafeAtomicAdd(&scal[2 + q], (float)__popcll(m));
        }
      }
      float acc[4][4];
#pragma unroll
      for (int q = 0; q < 4; ++q)
#pragma unroll
        for (int e = 0; e < 4; ++e) acc[q][e] = 0.f;
      const int rw = r0 + wave * 64;
      for (int k = 0; k < 64; ++k) {
        int row = rw + k;
        int g = sf[row];
        ushort4 v = ((const ushort4*)(znb + (size_t)row * DD))[lane];
        float f0 = bf2f(v.x), f1 = bf2f(v.y), f2 = bf2f(v.z), f3 = bf2f(v.w);
#pragma unroll
        for (int q = 0; q < 4; ++q) {
          acc[q][0] += (g == q) ? f0 : 0.f;
          acc[q][1] += (g == q) ? f1 : 0.f;
          acc[q][2] += (g == q) ? f2 : 0.f;
          acc[q][3] += (g == q) ? f3 : 0.f;
        }
      }
#pragma unroll
      for (int q = 0; q < 4; ++q)
#pragma unroll
        for (int e = 0; e < 4; ++e)
          unsafeAtomicAdd(&vsum[q * DD + lane * 4 + e], acc[q][e]);
    }
  } else {
    // ---- one symmetric den tile (inner code identical to R1/R8) ---------
    const bool diag = (tr == tc);
    const size_t rowbase = (size_t)tr * 128, colbase = (size_t)tc * 128;

    const int u = lane >> 3;
    const int cp = (lane & 7) ^ u;
    const int ri = 2 * u + (cp >> 2);
    const int kelem = (cp & 3) * 8;
    const int slot = ((((lane & 1) << 2) | (lane >> 4)) ^ ((lane >> 1) & 7));
    const int fragoff = ((lane & 15) >> 1) * 128 + slot * 16;
    const int wrow = wave & 1, wcol = wave >> 1;

    f32x4 zero = {0.f, 0.f, 0.f, 0.f};
    f32x4 acc[4][4];
#pragma unroll
    for (int i = 0; i < 4; ++i)
#pragma unroll
      for (int j = 0; j < 4; ++j) acc[i][j] = zero;

    auto stage = [&](int kt, int buf) {
#pragma unroll
      for (int j = 0; j < 2; ++j) {
        int is = wave * 2 + j;
        const unsigned short* gpa = znb + (rowbase + is * 16 + ri) * DD + kt * 32 + kelem;
        __builtin_amdgcn_global_load_lds((gvoid_t*)gpa, (lvoid_t*)&As[buf][is * 512], 16, 0, 0);
        const unsigned short* gpb = znb + (colbase + is * 16 + ri) * DD + kt * 32 + kelem;
        __builtin_amdgcn_global_load_lds((gvoid_t*)gpb, (lvoid_t*)&Bs[buf][is * 512], 16, 0, 0);
      }
    };

    stage(0, 0);
    __syncthreads();
#pragma unroll
    for (int kt = 0; kt < 8; ++kt) {
      if (kt < 7) stage(kt + 1, (kt + 1) & 1);
      const int buf = kt & 1;
      short8 af[4], bfr[4];
#pragma unroll
      for (int mi = 0; mi < 4; ++mi)
        af[mi] = *(const short8*)((const char*)&As[buf][0] + wrow * 4096 + mi * 1024 + fragoff);
#pragma unroll
      for (int ni = 0; ni < 4; ++ni)
        bfr[ni] = *(const short8*)((const char*)&Bs[buf][0] + wcol * 4096 + ni * 1024 + fragoff);
#pragma unroll
      for (int mi = 0; mi < 4; ++mi)
#pragma unroll
        for (int ni = 0; ni < 4; ++ni)
          acc[mi][ni] = __builtin_amdgcn_mfma_f32_16x16x32_bf16(af[mi], bfr[ni], acc[mi][ni], 0, 0, 0);
      __syncthreads();
    }

    // epilogue: e = exp(2S); row sums always; col sums for off-diag tiles.
    // C layout: col = lane&15, row = (lane>>4)*4 + reg.
    float rsum[4][4];
    float csum[4] = {0.f, 0.f, 0.f, 0.f};
#pragma unroll
    for (int mi = 0; mi < 4; ++mi)
#pragma unroll
      for (int r = 0; r < 4; ++r) rsum[mi][r] = 0.f;
#pragma unroll
    for (int mi = 0; mi < 4; ++mi)
#pragma unroll
      for (int ni = 0; ni < 4; ++ni)
#pragma unroll
        for (int r = 0; r < 4; ++r) {
          float e = __expf(2.0f * acc[mi][ni][r]);
          rsum[mi][r] += e;
          csum[ni] += e;
        }
#pragma unroll
    for (int m = 1; m < 16; m <<= 1)
#pragma unroll
      for (int mi = 0; mi < 4; ++mi)
#pragma unroll
        for (int r = 0; r < 4; ++r) rsum[mi][r] += __shfl_xor(rsum[mi][r], m);
    if ((lane & 15) == 0) {
      int h = lane >> 4;
#pragma unroll
      for (int mi = 0; mi < 4; ++mi)
#pragma unroll
        for (int r = 0; r < 4; ++r)
          unsafeAtomicAdd(&den[rowbase + wrow * 64 + mi * 16 + h * 4 + r], rsum[mi][r]);
    }
    if (!diag) {
#pragma unroll
      for (int m = 16; m < 64; m <<= 1)
#pragma unroll
        for (int ni = 0; ni < 4; ++ni) csum[ni] += __shfl_xor(csum[ni], m);
      if (lane < 16) {
#pragma unroll
        for (int ni = 0; ni < 4; ++ni)
          unsafeAtomicAdd(&den[colbase + wcol * 64 + ni * 16 + lane], csum[ni]);
      }
    }
    // pos trace: tiles (tr, tr+32) hold S[i][i+B] on their local diagonal.
    if (tc == tr + 32u && wrow == wcol) {
      float tacc = 0.f;
      int c = lane & 15, quad = lane >> 4;
      bool sel = (c >> 2) == quad;
#pragma unroll
      for (int mi = 0; mi < 4; ++mi)
#pragma unroll
        for (int r = 0; r < 4; ++r)
          tacc += (sel && ((c & 3) == r)) ? acc[mi][mi][r] : 0.f;
#pragma unroll
      for (int m = 32; m >= 1; m >>= 1) tacc += __shfl_xor(tacc, m);
      if (lane == 0) unsafeAtomicAdd(&scal[0], tacc);
    }
  }

  // ---- hierarchical arrive: leaf tc (64 arrivals) then root (64) ---------
  __syncthreads();
  if (tid == 0) {
    unsigned old = __hip_atomic_fetch_add(&leaves[tc * 32], 1u, __ATOMIC_RELEASE,
                                          __HIP_MEMORY_SCOPE_AGENT);
    int last = 0;
    if (old == 63u) {
      unsigned ro = __hip_atomic_fetch_add(root, 1u, __ATOMIC_RELEASE,
                                           __HIP_MEMORY_SCOPE_AGENT);
      last = (ro == 63u) ? 1 : 0;
    }
    *sh_lastp = last;
  }
  __syncthreads();
  if (!*sh_lastp) return;
  __builtin_amdgcn_fence(__ATOMIC_ACQUIRE, "agent");  // single buffer_inv, last block only

  // tail: log-reduce den, fairness from vsum, finalize
  const float e2 = __expf(2.0f);
  float ls = 0.f;
  for (int i = tid; i < TWOB; i += 256) ls += __logf(den[i] - e2);
#pragma unroll
  for (int m = 32; m >= 1; m >>= 1) ls += __shfl_xor(ls, m);
  if (lane == 0) sred[wave] = ls;
  float gp[4];
#pragma unroll
  for (int g = 0; g < 4; ++g) {
    float v = vsum[g * DD + tid];
    gp[g] = v * v;
#pragma unroll
    for (int m = 32; m >= 1; m >>= 1) gp[g] += __shfl_xor(gp[g], m);
  }
  if (lane == 0) {
#pragma unroll
    for (int g = 0; g < 4; ++g) sred[4 + wave * 4 + g] = gp[g];
  }
  __syncthreads();
  if (tid == 0) {
    float lsum = sred[0] + sred[1] + sred[2] + sred[3];
    float psum = scal[0];
    float contrastive = (lsum - 4.0f * psum) / (float)TWOB;
    float fsum = 0.f;
    int uniq = 0;
#pragma unroll
    for (int q = 0; q < 4; ++q) {
      float gsq = sred[4 + q] + sred[8 + q] + sred[12 + q] + sred[16 + q];
      float c = scal[2 + q];
      if (c > 0.5f) uniq++;
      if (c > 1.5f) fsum += gsq / (c * (c - 1.0f));
    }
    out[0] = contrastive + 0.1f * (fsum / (uniq > 0 ? (float)uniq : 1.0f));
  }
}

extern "C" void kernel_launch(void* const* d_in, const int* in_sizes, int n_in,
                              void* d_out, int out_size, void* d_ws, size_t ws_size,
                              hipStream_t stream) {
  const float* zi = (const float*)d_in[0];
  const float* zj = (const float*)d_in[1];
  const int* sf = (const int*)d_in[2];
  float* out = (float*)d_out;
  char* ws = (char*)d_ws;
  float* wsf = (float*)ws;                              // den/vsum/scal/arrive region
  unsigned short* znb = (unsigned short*)(ws + 65536);  // 8192x256 bf16 (4MB)

  hipLaunchKernelGGL(norm_kernel, dim3(1024), dim3(256), 0, stream, zi, zj, wsf, znb);
  hipLaunchKernelGGL(main_kernel, dim3(64, 64), dim3(256), 0, stream, sf, wsf, znb, out);
}

// Round 10
// 140.674 us; speedup vs baseline: 1.3019x; 1.3019x over previous
//
#include <hip/hip_runtime.h>
#include <hip/hip_bf16.h>

typedef __attribute__((ext_vector_type(8))) short short8;
typedef __attribute__((ext_vector_type(4))) float f32x4;
typedef __attribute__((address_space(1))) const void gvoid_t;
typedef __attribute__((address_space(3))) void lvoid_t;

#define NB 4096   // B
#define DD 256    // D
#define TWOB 8192
#define NTILES 2080u   // 64*65/2 symmetric 128x128 tiles
#define GSUM_BLOCKS 16

__device__ __forceinline__ unsigned short f2bf(float f) {
  unsigned int u = __float_as_uint(f);
  u += 0x7fffu + ((u >> 16) & 1u);
  return (unsigned short)(u >> 16);
}
__device__ __forceinline__ float bf2f(unsigned short s) {
  return __uint_as_float(((unsigned int)s) << 16);
}

// ws float layout: [0..8191] den, [8192..9215] vsum, scal = wsf+9216 (16):
//   scal[0]=psum, scal[2..5]=counts. Zeroed by kernel A blocks 0..36.
//
// R9 post-mortem (the unifying theory for R4-R9's 2.5x per-tile slowdown):
// any __syncthreads or ordered atomic AFTER the epilogue's den atomics makes
// each wave drain vmcnt(0) -- i.e. wait for its own fire-and-forget den
// atomics, which are queued behind other blocks' atomics on the same hot
// den cachelines -- while holding the CU slot. R1's blocks hit s_endpgm
// with atomics in flight and retire instantly. Therefore: tile blocks now
// end IMMEDIATELY after the epilogue (no arrive, no tail, no counters);
// the tail is a separate 1-block dispatch (kernel boundary = sync).

// ---------------- kernel A: zero accum; normalize -> znb bf16; pos --------
__global__ __launch_bounds__(256) void norm_kernel(const float* __restrict__ zi,
                                                   const float* __restrict__ zj,
                                                   float* __restrict__ wsf,
                                                   unsigned short* __restrict__ znb) {
  __shared__ float sred[4];
  if (blockIdx.x < 37) wsf[blockIdx.x * 256 + threadIdx.x] = 0.f;
  float* scal = wsf + 9216;
  const int lane = threadIdx.x & 63, wave = threadIdx.x >> 6;
  const int i = blockIdx.x * 4 + wave;

  float4 a = ((const float4*)(zi + (size_t)i * DD))[lane];
  float4 b = ((const float4*)(zj + (size_t)i * DD))[lane];
  float sa = a.x * a.x + a.y * a.y + a.z * a.z + a.w * a.w;
  float sb = b.x * b.x + b.y * b.y + b.z * b.z + b.w * b.w;
  float sab = a.x * b.x + a.y * b.y + a.z * b.z + a.w * b.w;
#pragma unroll
  for (int m = 32; m >= 1; m >>= 1) {
    sa += __shfl_xor(sa, m);
    sb += __shfl_xor(sb, m);
    sab += __shfl_xor(sab, m);
  }
  float ra = 1.0f / fmaxf(sqrtf(sa), 1e-8f);
  float rb = 1.0f / fmaxf(sqrtf(sb), 1e-8f);
  ushort4 oa, ob;
  oa.x = f2bf(a.x * ra); oa.y = f2bf(a.y * ra); oa.z = f2bf(a.z * ra); oa.w = f2bf(a.w * ra);
  ob.x = f2bf(b.x * rb); ob.y = f2bf(b.y * rb); ob.z = f2bf(b.z * rb); ob.w = f2bf(b.w * rb);
  ((ushort4*)(znb + (size_t)i * DD))[lane] = oa;
  ((ushort4*)(znb + (size_t)(i + NB) * DD))[lane] = ob;

  if (lane == 0) sred[wave] = sab * ra * rb;  // exact fp32 pos (row i)
  __syncthreads();
  if (threadIdx.x == 0)
    unsafeAtomicAdd(&scal[0], sred[0] + sred[1] + sred[2] + sred[3]);
}

// ---------------- kernel B: symmetric den tiles + gsum; NO sync, NO tail --
__global__ __launch_bounds__(256, 3) void den_kernel(const int* __restrict__ sf,
                                                     float* __restrict__ wsf,
                                                     const unsigned short* __restrict__ znb) {
  __shared__ __align__(16) unsigned short As[2][4096];  // 2 x 8KB = 32768 LDS
  __shared__ __align__(16) unsigned short Bs[2][4096];

  float* den = wsf;
  float* vsum = wsf + 8192;
  float* scal = wsf + 9216;

  const int tid = threadIdx.x;
  const int lane = tid & 63, wave = tid >> 6;

  if (blockIdx.x >= NTILES) {
    // ---- gsum role (16 blocks at grid end): 256 rows each ---------------
    const int r0 = (int)(blockIdx.x - NTILES) * 256;
    {
      int g = sf[r0 + tid];
#pragma unroll
      for (int q = 0; q < 4; ++q) {
        unsigned long long m = __ballot(g == q);
        if (lane == 0) unsafeAtomicAdd(&scal[2 + q], (float)__popcll(m));
      }
    }
    float acc[4][4];
#pragma unroll
    for (int q = 0; q < 4; ++q)
#pragma unroll
      for (int e = 0; e < 4; ++e) acc[q][e] = 0.f;
    const int rw = r0 + wave * 64;
    for (int k = 0; k < 64; ++k) {
      int row = rw + k;
      int g = sf[row];
      ushort4 v = ((const ushort4*)(znb + (size_t)row * DD))[lane];
      float f0 = bf2f(v.x), f1 = bf2f(v.y), f2 = bf2f(v.z), f3 = bf2f(v.w);
#pragma unroll
      for (int q = 0; q < 4; ++q) {
        acc[q][0] += (g == q) ? f0 : 0.f;
        acc[q][1] += (g == q) ? f1 : 0.f;
        acc[q][2] += (g == q) ? f2 : 0.f;
        acc[q][3] += (g == q) ? f3 : 0.f;
      }
    }
#pragma unroll
    for (int q = 0; q < 4; ++q)
#pragma unroll
      for (int e = 0; e < 4; ++e)
        unsafeAtomicAdd(&vsum[q * DD + lane * 4 + e], acc[q][e]);
    return;
  }

  // ---- one symmetric den tile (inner code identical to R1) --------------
  unsigned t = blockIdx.x;
  unsigned tr = 0;
  while (t >= 64u - tr) { t -= 64u - tr; ++tr; }
  unsigned tc = tr + t;
  const bool diag = (tr == tc);
  const size_t rowbase = (size_t)tr * 128, colbase = (size_t)tc * 128;

  const int u = lane >> 3;
  const int cp = (lane & 7) ^ u;
  const int ri = 2 * u + (cp >> 2);
  const int kelem = (cp & 3) * 8;
  const int slot = ((((lane & 1) << 2) | (lane >> 4)) ^ ((lane >> 1) & 7));
  const int fragoff = ((lane & 15) >> 1) * 128 + slot * 16;
  const int wrow = wave & 1, wcol = wave >> 1;

  f32x4 zero = {0.f, 0.f, 0.f, 0.f};
  f32x4 acc[4][4];
#pragma unroll
  for (int i = 0; i < 4; ++i)
#pragma unroll
    for (int j = 0; j < 4; ++j) acc[i][j] = zero;

  auto stage = [&](int kt, int buf) {
#pragma unroll
    for (int j = 0; j < 2; ++j) {
      int is = wave * 2 + j;
      const unsigned short* gpa = znb + (rowbase + is * 16 + ri) * DD + kt * 32 + kelem;
      __builtin_amdgcn_global_load_lds((gvoid_t*)gpa, (lvoid_t*)&As[buf][is * 512], 16, 0, 0);
      const unsigned short* gpb = znb + (colbase + is * 16 + ri) * DD + kt * 32 + kelem;
      __builtin_amdgcn_global_load_lds((gvoid_t*)gpb, (lvoid_t*)&Bs[buf][is * 512], 16, 0, 0);
    }
  };

  stage(0, 0);
  __syncthreads();
#pragma unroll
  for (int kt = 0; kt < 8; ++kt) {
    if (kt < 7) stage(kt + 1, (kt + 1) & 1);
    const int buf = kt & 1;
    short8 af[4], bfr[4];
#pragma unroll
    for (int mi = 0; mi < 4; ++mi)
      af[mi] = *(const short8*)((const char*)&As[buf][0] + wrow * 4096 + mi * 1024 + fragoff);
#pragma unroll
    for (int ni = 0; ni < 4; ++ni)
      bfr[ni] = *(const short8*)((const char*)&Bs[buf][0] + wcol * 4096 + ni * 1024 + fragoff);
#pragma unroll
    for (int mi = 0; mi < 4; ++mi)
#pragma unroll
      for (int ni = 0; ni < 4; ++ni)
        acc[mi][ni] = __builtin_amdgcn_mfma_f32_16x16x32_bf16(af[mi], bfr[ni], acc[mi][ni], 0, 0, 0);
    __syncthreads();
  }

  // epilogue: e = exp(2S); row sums always; col sums for off-diag tiles.
  // C layout: col = lane&15, row = (lane>>4)*4 + reg. Then the block ENDS --
  // no barrier, no arrive: atomics drain after s_endpgm (R1 behavior).
  float rsum[4][4];
  float csum[4] = {0.f, 0.f, 0.f, 0.f};
#pragma unroll
  for (int mi = 0; mi < 4; ++mi)
#pragma unroll
    for (int r = 0; r < 4; ++r) rsum[mi][r] = 0.f;
#pragma unroll
  for (int mi = 0; mi < 4; ++mi)
#pragma unroll
    for (int ni = 0; ni < 4; ++ni)
#pragma unroll
      for (int r = 0; r < 4; ++r) {
        float e = __expf(2.0f * acc[mi][ni][r]);
        rsum[mi][r] += e;
        csum[ni] += e;
      }
#pragma unroll
  for (int m = 1; m < 16; m <<= 1)
#pragma unroll
    for (int mi = 0; mi < 4; ++mi)
#pragma unroll
      for (int r = 0; r < 4; ++r) rsum[mi][r] += __shfl_xor(rsum[mi][r], m);
  if ((lane & 15) == 0) {
    int h = lane >> 4;
#pragma unroll
    for (int mi = 0; mi < 4; ++mi)
#pragma unroll
      for (int r = 0; r < 4; ++r)
        unsafeAtomicAdd(&den[rowbase + wrow * 64 + mi * 16 + h * 4 + r], rsum[mi][r]);
  }
  if (!diag) {
#pragma unroll
    for (int m = 16; m < 64; m <<= 1)
#pragma unroll
      for (int ni = 0; ni < 4; ++ni) csum[ni] += __shfl_xor(csum[ni], m);
    if (lane < 16) {
#pragma unroll
      for (int ni = 0; ni < 4; ++ni)
        unsafeAtomicAdd(&den[colbase + wcol * 64 + ni * 16 + lane], csum[ni]);
    }
  }
}

// ---------------- kernel C: tail (1 block) --------------------------------
__global__ __launch_bounds__(256) void tail_kernel(const float* __restrict__ wsf,
                                                   float* __restrict__ out) {
  __shared__ float sred[32];
  const float* den = wsf;
  const float* vsum = wsf + 8192;
  const float* scal = wsf + 9216;
  const int tid = threadIdx.x;
  const int lane = tid & 63, wave = tid >> 6;

  const float e2 = __expf(2.0f);
  float ls = 0.f;
  for (int i = tid; i < TWOB; i += 256) ls += __logf(den[i] - e2);
#pragma unroll
  for (int m = 32; m >= 1; m >>= 1) ls += __shfl_xor(ls, m);
  if (lane == 0) sred[wave] = ls;
  float gp[4];
#pragma unroll
  for (int g = 0; g < 4; ++g) {
    float v = vsum[g * DD + tid];
    gp[g] = v * v;
#pragma unroll
    for (int m = 32; m >= 1; m >>= 1) gp[g] += __shfl_xor(gp[g], m);
  }
  if (lane == 0) {
#pragma unroll
    for (int g = 0; g < 4; ++g) sred[4 + wave * 4 + g] = gp[g];
  }
  __syncthreads();
  if (tid == 0) {
    float lsum = sred[0] + sred[1] + sred[2] + sred[3];
    float psum = scal[0];
    float contrastive = (lsum - 4.0f * psum) / (float)TWOB;
    float fsum = 0.f;
    int uniq = 0;
#pragma unroll
    for (int q = 0; q < 4; ++q) {
      float gsq = sred[4 + q] + sred[8 + q] + sred[12 + q] + sred[16 + q];
      float c = scal[2 + q];
      if (c > 0.5f) uniq++;
      if (c > 1.5f) fsum += gsq / (c * (c - 1.0f));
    }
    out[0] = contrastive + 0.1f * (fsum / (uniq > 0 ? (float)uniq : 1.0f));
  }
}

extern "C" void kernel_launch(void* const* d_in, const int* in_sizes, int n_in,
                              void* d_out, int out_size, void* d_ws, size_t ws_size,
                              hipStream_t stream) {
  const float* zi = (const float*)d_in[0];
  const float* zj = (const float*)d_in[1];
  const int* sf = (const int*)d_in[2];
  float* out = (float*)d_out;
  char* ws = (char*)d_ws;
  float* wsf = (float*)ws;                              // den/vsum/scal region
  unsigned short* znb = (unsigned short*)(ws + 65536);  // 8192x256 bf16 (4MB)

  hipLaunchKernelGGL(norm_kernel, dim3(1024), dim3(256), 0, stream, zi, zj, wsf, znb);
  hipLaunchKernelGGL(den_kernel, dim3(NTILES + GSUM_BLOCKS), dim3(256), 0, stream, sf, wsf, znb);
  hipLaunchKernelGGL(tail_kernel, dim3(1), dim3(256), 0, stream, wsf, out);
}

// Round 11
// 133.893 us; speedup vs baseline: 1.3678x; 1.0506x over previous
//
#include <hip/hip_runtime.h>
#include <hip/hip_bf16.h>

typedef __attribute__((ext_vector_type(8))) short short8;
typedef __attribute__((ext_vector_type(4))) float f32x4;
typedef __attribute__((address_space(1))) const void gvoid_t;
typedef __attribute__((address_space(3))) void lvoid_t;

#define NB 4096   // B
#define DD 256    // D
#define TWOB 8192
#define NTILES 2080u   // 64*65/2 symmetric 128x128 tiles
#define GSUM_BLOCKS 16

__device__ __forceinline__ unsigned short f2bf(float f) {
  unsigned int u = __float_as_uint(f);
  u += 0x7fffu + ((u >> 16) & 1u);
  return (unsigned short)(u >> 16);
}
__device__ __forceinline__ float bf2f(unsigned short s) {
  return __uint_as_float(((unsigned int)s) << 16);
}

// ws layout (bytes):
//   [0, 36864)        wsf floats: [0..8191] den, scal = wsf+9216 (scal[0]=psum)
//   [65536, 4259840)  znb: 8192x256 bf16
//   [4259840, +64KB)  vsum_part[16][4][256] f32 (plain stores, no zeroing needed)
//   then cnt_part[16][4] int
//
// R10 post-mortem: the per-tile "2x slowdown" of R4-R10 was never the tiles --
// it was the 16 gsum blocks' 65K contended atomics (~2000 RMWs per vsum
// cacheline, serialized) running as a SERIAL TAIL of the den kernel (they
// were the last 16 blocks dispatched). Fix: gsum is atomic-free (LDS-reduce
// + private partial buffers, plain stores) and placed FIRST in the grid so
// its ~4us overlaps round 1 of the tiles. Tail kernel sums 16 partials.

// ---------------- kernel A: zero accum; normalize -> znb bf16; pos --------
__global__ __launch_bounds__(256) void norm_kernel(const float* __restrict__ zi,
                                                   const float* __restrict__ zj,
                                                   float* __restrict__ wsf,
                                                   unsigned short* __restrict__ znb) {
  __shared__ float sred[4];
  if (blockIdx.x < 37) wsf[blockIdx.x * 256 + threadIdx.x] = 0.f;
  float* scal = wsf + 9216;
  const int lane = threadIdx.x & 63, wave = threadIdx.x >> 6;
  const int i = blockIdx.x * 4 + wave;

  float4 a = ((const float4*)(zi + (size_t)i * DD))[lane];
  float4 b = ((const float4*)(zj + (size_t)i * DD))[lane];
  float sa = a.x * a.x + a.y * a.y + a.z * a.z + a.w * a.w;
  float sb = b.x * b.x + b.y * b.y + b.z * b.z + b.w * b.w;
  float sab = a.x * b.x + a.y * b.y + a.z * b.z + a.w * b.w;
#pragma unroll
  for (int m = 32; m >= 1; m >>= 1) {
    sa += __shfl_xor(sa, m);
    sb += __shfl_xor(sb, m);
    sab += __shfl_xor(sab, m);
  }
  float ra = 1.0f / fmaxf(sqrtf(sa), 1e-8f);
  float rb = 1.0f / fmaxf(sqrtf(sb), 1e-8f);
  ushort4 oa, ob;
  oa.x = f2bf(a.x * ra); oa.y = f2bf(a.y * ra); oa.z = f2bf(a.z * ra); oa.w = f2bf(a.w * ra);
  ob.x = f2bf(b.x * rb); ob.y = f2bf(b.y * rb); ob.z = f2bf(b.z * rb); ob.w = f2bf(b.w * rb);
  ((ushort4*)(znb + (size_t)i * DD))[lane] = oa;
  ((ushort4*)(znb + (size_t)(i + NB) * DD))[lane] = ob;

  if (lane == 0) sred[wave] = sab * ra * rb;  // exact fp32 pos (row i)
  __syncthreads();
  if (threadIdx.x == 0)
    unsafeAtomicAdd(&scal[0], sred[0] + sred[1] + sred[2] + sred[3]);
}

// ---------------- kernel B: gsum (first, atomic-free) + den tiles ---------
__global__ __launch_bounds__(256, 3) void den_kernel(const int* __restrict__ sf,
                                                     float* __restrict__ wsf,
                                                     const unsigned short* __restrict__ znb,
                                                     float* __restrict__ vsum_part,
                                                     int* __restrict__ cnt_part) {
  __shared__ __align__(16) unsigned short As[2][4096];  // 2 x 8KB = 32768 LDS
  __shared__ __align__(16) unsigned short Bs[2][4096];

  float* den = wsf;

  const int tid = threadIdx.x;
  const int lane = tid & 63, wave = tid >> 6;

  if (blockIdx.x < GSUM_BLOCKS) {
    // ---- gsum role: 256 rows, LDS reduce, PLAIN stores to private partial
    const int b = blockIdx.x;
    const int r0 = b * 256;
    float acc[4][4];
#pragma unroll
    for (int q = 0; q < 4; ++q)
#pragma unroll
      for (int e = 0; e < 4; ++e) acc[q][e] = 0.f;
    int cnt[4] = {0, 0, 0, 0};
    const int rw = r0 + wave * 64;
    for (int k = 0; k < 64; ++k) {
      int row = rw + k;
      int g = sf[row];
      ushort4 v = ((const ushort4*)(znb + (size_t)row * DD))[lane];
      float f0 = bf2f(v.x), f1 = bf2f(v.y), f2 = bf2f(v.z), f3 = bf2f(v.w);
#pragma unroll
      for (int q = 0; q < 4; ++q) {
        bool sel = (g == q);
        acc[q][0] += sel ? f0 : 0.f;
        acc[q][1] += sel ? f1 : 0.f;
        acc[q][2] += sel ? f2 : 0.f;
        acc[q][3] += sel ? f3 : 0.f;
        cnt[q] += sel ? 1 : 0;
      }
    }
    // cross-wave reduce via LDS (As = 16KB exactly fits 4x4x64 float4)
    float4* lsd = (float4*)&As[0][0];
    int* lcnt = (int*)&Bs[0][0];
#pragma unroll
    for (int q = 0; q < 4; ++q) {
      float4 t;
      t.x = acc[q][0]; t.y = acc[q][1]; t.z = acc[q][2]; t.w = acc[q][3];
      lsd[(wave * 4 + q) * 64 + lane] = t;
    }
    if (lane == 0) {
#pragma unroll
      for (int q = 0; q < 4; ++q) lcnt[wave * 4 + q] = cnt[q];
    }
    __syncthreads();
    {
      int g = tid >> 6, l = tid & 63;
      float4 s0 = lsd[(0 + g) * 64 + l];
      float4 s1 = lsd[(4 + g) * 64 + l];
      float4 s2 = lsd[(8 + g) * 64 + l];
      float4 s3 = lsd[(12 + g) * 64 + l];
      float4 s;
      s.x = s0.x + s1.x + s2.x + s3.x;
      s.y = s0.y + s1.y + s2.y + s3.y;
      s.z = s0.z + s1.z + s2.z + s3.z;
      s.w = s0.w + s1.w + s2.w + s3.w;
      ((float4*)(vsum_part + (size_t)(b * 4 + g) * 256))[l] = s;
      if (tid < 4)
        cnt_part[b * 4 + tid] = lcnt[tid] + lcnt[4 + tid] + lcnt[8 + tid] + lcnt[12 + tid];
    }
    return;
  }

  // ---- one symmetric den tile (identical to R10; ends at s_endpgm) ------
  unsigned t = blockIdx.x - GSUM_BLOCKS;
  unsigned tr = 0;
  while (t >= 64u - tr) { t -= 64u - tr; ++tr; }
  unsigned tc = tr + t;
  const bool diag = (tr == tc);
  const size_t rowbase = (size_t)tr * 128, colbase = (size_t)tc * 128;

  const int u = lane >> 3;
  const int cp = (lane & 7) ^ u;
  const int ri = 2 * u + (cp >> 2);
  const int kelem = (cp & 3) * 8;
  const int slot = ((((lane & 1) << 2) | (lane >> 4)) ^ ((lane >> 1) & 7));
  const int fragoff = ((lane & 15) >> 1) * 128 + slot * 16;
  const int wrow = wave & 1, wcol = wave >> 1;

  f32x4 zero = {0.f, 0.f, 0.f, 0.f};
  f32x4 acc[4][4];
#pragma unroll
  for (int i = 0; i < 4; ++i)
#pragma unroll
    for (int j = 0; j < 4; ++j) acc[i][j] = zero;

  auto stage = [&](int kt, int buf) {
#pragma unroll
    for (int j = 0; j < 2; ++j) {
      int is = wave * 2 + j;
      const unsigned short* gpa = znb + (rowbase + is * 16 + ri) * DD + kt * 32 + kelem;
      __builtin_amdgcn_global_load_lds((gvoid_t*)gpa, (lvoid_t*)&As[buf][is * 512], 16, 0, 0);
      const unsigned short* gpb = znb + (colbase + is * 16 + ri) * DD + kt * 32 + kelem;
      __builtin_amdgcn_global_load_lds((gvoid_t*)gpb, (lvoid_t*)&Bs[buf][is * 512], 16, 0, 0);
    }
  };

  stage(0, 0);
  __syncthreads();
#pragma unroll
  for (int kt = 0; kt < 8; ++kt) {
    if (kt < 7) stage(kt + 1, (kt + 1) & 1);
    const int buf = kt & 1;
    short8 af[4], bfr[4];
#pragma unroll
    for (int mi = 0; mi < 4; ++mi)
      af[mi] = *(const short8*)((const char*)&As[buf][0] + wrow * 4096 + mi * 1024 + fragoff);
#pragma unroll
    for (int ni = 0; ni < 4; ++ni)
      bfr[ni] = *(const short8*)((const char*)&Bs[buf][0] + wcol * 4096 + ni * 1024 + fragoff);
#pragma unroll
    for (int mi = 0; mi < 4; ++mi)
#pragma unroll
      for (int ni = 0; ni < 4; ++ni)
        acc[mi][ni] = __builtin_amdgcn_mfma_f32_16x16x32_bf16(af[mi], bfr[ni], acc[mi][ni], 0, 0, 0);
    __syncthreads();
  }

  // epilogue: e = exp(2S); row sums always; col sums for off-diag tiles.
  // C layout: col = lane&15, row = (lane>>4)*4 + reg. Block ends right after
  // the atomics (drain after s_endpgm, R1 behavior).
  float rsum[4][4];
  float csum[4] = {0.f, 0.f, 0.f, 0.f};
#pragma unroll
  for (int mi = 0; mi < 4; ++mi)
#pragma unroll
    for (int r = 0; r < 4; ++r) rsum[mi][r] = 0.f;
#pragma unroll
  for (int mi = 0; mi < 4; ++mi)
#pragma unroll
    for (int ni = 0; ni < 4; ++ni)
#pragma unroll
      for (int r = 0; r < 4; ++r) {
        float e = __expf(2.0f * acc[mi][ni][r]);
        rsum[mi][r] += e;
        csum[ni] += e;
      }
#pragma unroll
  for (int m = 1; m < 16; m <<= 1)
#pragma unroll
    for (int mi = 0; mi < 4; ++mi)
#pragma unroll
      for (int r = 0; r < 4; ++r) rsum[mi][r] += __shfl_xor(rsum[mi][r], m);
  if ((lane & 15) == 0) {
    int h = lane >> 4;
#pragma unroll
    for (int mi = 0; mi < 4; ++mi)
#pragma unroll
      for (int r = 0; r < 4; ++r)
        unsafeAtomicAdd(&den[rowbase + wrow * 64 + mi * 16 + h * 4 + r], rsum[mi][r]);
  }
  if (!diag) {
#pragma unroll
    for (int m = 16; m < 64; m <<= 1)
#pragma unroll
      for (int ni = 0; ni < 4; ++ni) csum[ni] += __shfl_xor(csum[ni], m);
    if (lane < 16) {
#pragma unroll
      for (int ni = 0; ni < 4; ++ni)
        unsafeAtomicAdd(&den[colbase + wcol * 64 + ni * 16 + lane], csum[ni]);
    }
  }
}

// ---------------- kernel C: tail (1 block) --------------------------------
__global__ __launch_bounds__(256) void tail_kernel(const float* __restrict__ wsf,
                                                   const float* __restrict__ vsum_part,
                                                   const int* __restrict__ cnt_part,
                                                   float* __restrict__ out) {
  __shared__ float sred[32];
  const float* den = wsf;
  const float* scal = wsf + 9216;
  const int tid = threadIdx.x;
  const int lane = tid & 63, wave = tid >> 6;

  const float e2 = __expf(2.0f);
  float ls = 0.f;
  for (int i = tid; i < TWOB; i += 256) ls += __logf(den[i] - e2);
#pragma unroll
  for (int m = 32; m >= 1; m >>= 1) ls += __shfl_xor(ls, m);
  if (lane == 0) sred[wave] = ls;

  float gp[4];
#pragma unroll
  for (int g = 0; g < 4; ++g) {
    float v = 0.f;
#pragma unroll
    for (int b = 0; b < 16; ++b) v += vsum_part[(size_t)(b * 4 + g) * 256 + tid];
    gp[g] = v * v;
#pragma unroll
    for (int m = 32; m >= 1; m >>= 1) gp[g] += __shfl_xor(gp[g], m);
  }
  if (lane == 0) {
#pragma unroll
    for (int g = 0; g < 4; ++g) sred[4 + wave * 4 + g] = gp[g];
  }
  __syncthreads();
  if (tid == 0) {
    float lsum = sred[0] + sred[1] + sred[2] + sred[3];
    float psum = scal[0];
    float contrastive = (lsum - 4.0f * psum) / (float)TWOB;
    float fsum = 0.f;
    int uniq = 0;
#pragma unroll
    for (int q = 0; q < 4; ++q) {
      int ci = 0;
#pragma unroll
      for (int b = 0; b < 16; ++b) ci += cnt_part[b * 4 + q];
      float gsq = sred[4 + q] + sred[8 + q] + sred[12 + q] + sred[16 + q];
      float c = (float)ci;
      if (ci > 0) uniq++;
      if (ci > 1) fsum += gsq / (c * (c - 1.0f));
    }
    out[0] = contrastive + 0.1f * (fsum / (uniq > 0 ? (float)uniq : 1.0f));
  }
}

extern "C" void kernel_launch(void* const* d_in, const int* in_sizes, int n_in,
                              void* d_out, int out_size, void* d_ws, size_t ws_size,
                              hipStream_t stream) {
  const float* zi = (const float*)d_in[0];
  const float* zj = (const float*)d_in[1];
  const int* sf = (const int*)d_in[2];
  float* out = (float*)d_out;
  char* ws = (char*)d_ws;
  float* wsf = (float*)ws;                              // den/scal region
  unsigned short* znb = (unsigned short*)(ws + 65536);  // 8192x256 bf16 (4MB)
  float* vsum_part = (float*)(ws + 65536 + 4194304);    // 16x4x256 f32 (64KB)
  int* cnt_part = (int*)(ws + 65536 + 4194304 + 65536); // 16x4 int

  hipLaunchKernelGGL(norm_kernel, dim3(1024), dim3(256), 0, stream, zi, zj, wsf, znb);
  hipLaunchKernelGGL(den_kernel, dim3(NTILES + GSUM_BLOCKS), dim3(256), 0, stream,
                     sf, wsf, znb, vsum_part, cnt_part);
  hipLaunchKernelGGL(tail_kernel, dim3(1), dim3(256), 0, stream, wsf, vsum_part, cnt_part, out);
}